// Round 13
// baseline (414.838 us; speedup 1.0000x reference)
//
#include <hip/hip_runtime.h>
#include <hip/hip_bf16.h>
#include <stdint.h>

// ---------- types & helpers ----------
typedef __attribute__((ext_vector_type(4))) float f32x4;
typedef __attribute__((ext_vector_type(8))) short s16x8;      // MFMA bf16 frag (8 bf16)
typedef __attribute__((ext_vector_type(8))) unsigned short u16x8;
typedef __attribute__((ext_vector_type(4))) unsigned short u16x4;

static __device__ __forceinline__ float b2f(unsigned short u) {
  union { unsigned int i; float f; } v; v.i = ((unsigned int)u) << 16; return v.f;
}
static __device__ __forceinline__ unsigned short f2b(float f) {
  unsigned int x = __float_as_uint(f);
  return (unsigned short)((x + 0x7fffu + ((x >> 16) & 1u)) >> 16);  // RNE
}

typedef __attribute__((address_space(1))) const void gconst_t;
typedef __attribute__((address_space(3))) void lds_t;
static __device__ __forceinline__ void gload_lds16(const void* g, void* l) {
  __builtin_amdgcn_global_load_lds((gconst_t*)g, (lds_t*)l, 16, 0, 0);
}

template<int N>
static __device__ __forceinline__ void vmwait() {
  asm volatile("s_waitcnt vmcnt(%0)" :: "n"(N) : "memory");
}
static __device__ __forceinline__ void barmid() {
  __builtin_amdgcn_sched_barrier(0);
  __builtin_amdgcn_s_barrier();
  asm volatile("s_waitcnt lgkmcnt(0)" ::: "memory");
  __builtin_amdgcn_sched_barrier(0);
}
static __device__ __forceinline__ void barend() {
  __builtin_amdgcn_sched_barrier(0);
  __builtin_amdgcn_s_barrier();
}

struct GemmP {
  const unsigned short* A; const unsigned short* B; void* C;
  long sA, sB, sC;                 // batch strides (elements)
  int M, N, K, lda, ldb, ldc;
  int causal, kend_mode, swapxy;
  int gxs, gys, qchunk;            // log2 decode of wg, nwg/8
  const float* uvec; const float* vvec;
  unsigned short* qv_out; unsigned short* kk_out; float invtau;
  const float* rinv; const unsigned short* gate;
  const unsigned short* bds; float* stats;
};

// ---------- ring-3 256x128 GEMM (merged single-barrier K-loop) — wv ----------
// 8 waves (4M x 2N), per-wave C 64x64. LDS 3 slots x {A0,A1,B} = 144KB.
// One {16 ds_read + prefetch -> barrier+lgkm0 -> 32 MFMA -> counted vmcnt ->
// barrier} per K-tile of 64. vmcnt(6) = one tile in flight. PAIR=1: block
// runs M-tiles (15-xx) then (xx) — causal kends sum constant.
// EPI: 0=bf16  1=fp32  2=silu bf16  4=wv(*rinv*gate)
template<int PAIR, int EPI>
__launch_bounds__(512, 2)
__global__ void gemm8p128_k(GemmP p) {
  __shared__ unsigned short L[3][3][8192];   // [slot][A0,A1,B][128*64]
  const int lin = (int)blockIdx.x + (int)gridDim.x * ((int)blockIdx.y + (int)gridDim.y * (int)blockIdx.z);
  const int wg = (lin & 7) * p.qchunk + (lin >> 3);
  const int xx = wg & ((1 << p.gxs) - 1);
  const int yy = (wg >> p.gxs) & ((1 << p.gys) - 1);
  const int b  = wg >> (p.gxs + p.gys);
  const int jj = PAIR ? yy : (p.swapxy ? xx : yy);
  const int j0 = jj * 128;
  const unsigned short* Bg0 = p.B + (long)b * p.sB + (long)j0 * p.ldb;
  const int lda = p.lda, ldb = p.ldb;

  const int tid = threadIdx.x;
  const int w = tid >> 6, l = tid & 63;
  const int wr = w >> 1, wc = w & 1;
  const int fr = l & 15, fq = l >> 4;

  const int sx = (fr & 7) << 4;        // 3-bit row XOR (granule bits 4-6)
  const int abase = ((((wr & 1) << 13) + (fr << 7) + (fq << 4))) ^ sx;
  const int bbase = (((wc << 13) + (fr << 7) + (fq << 4))) ^ sx;

  const int passes = PAIR ? 2 : 1;
  for (int ps = 0; ps < passes; ++ps) {
    const int ii = PAIR ? (ps ? xx : (15 - xx)) : (p.swapxy ? yy : xx);
    const int i0 = ii * 256;
    const unsigned short* Ag = p.A + (long)b * p.sA + (long)i0 * lda;
    const int kend = p.kend_mode ? min(p.K, i0 + 256) : p.K;
    const int NT = kend >> 6;

    auto stA = [&](int slot, int h, int t) {
#pragma unroll
      for (int u = 0; u < 2; ++u) {
        const int sl = u * 512 + tid, r = sl >> 3, g = sl & 7;
        const int gs = g ^ (r & 7);
        gload_lds16(Ag + (long)(h * 128 + r) * lda + t * 64 + gs * 8, &L[slot][h][sl * 8]);
      }
    };
    auto stB = [&](int slot, int bh, int t) {
      const int r = tid >> 3, g = tid & 7;
      const int rloc = bh * 64 + r;
      const int gs = g ^ (rloc & 7);
      gload_lds16(Bg0 + (long)rloc * ldb + t * 64 + gs * 8, &L[slot][2][bh * 4096 + tid * 8]);
    };

    f32x4 acc[4][4];
#pragma unroll
    for (int m = 0; m < 4; ++m)
#pragma unroll
      for (int n = 0; n < 4; ++n) acc[m][n] = (f32x4){0.f, 0.f, 0.f, 0.f};
    s16x8 a[4][2], bA[2][2], bB[2][2];

    auto rdA = [&](int slot) {
      const int reg = wr >> 1;
#pragma unroll
      for (int m = 0; m < 4; ++m)
#pragma unroll
        for (int ks = 0; ks < 2; ++ks)
          a[m][ks] = *(const s16x8*)((const char*)&L[slot][reg][0] +
                                     ((abase ^ (ks << 6)) | (m << 11)));
    };
    auto rdB = [&](int slot, int nq, s16x8 (&bb)[2][2]) {
#pragma unroll
      for (int n = 0; n < 2; ++n)
#pragma unroll
        for (int ks = 0; ks < 2; ++ks)
          bb[n][ks] = *(const s16x8*)((const char*)&L[slot][2][0] +
                                      ((bbase ^ (ks << 6)) | ((nq * 2 + n) << 11)));
    };
    auto mm = [&](int nq, s16x8 (&bb)[2][2]) {
#pragma unroll
      for (int m = 0; m < 4; ++m)
#pragma unroll
        for (int n = 0; n < 2; ++n)
#pragma unroll
          for (int ks = 0; ks < 2; ++ks)
            acc[m][nq * 2 + n] =
                __builtin_amdgcn_mfma_f32_16x16x32_bf16(a[m][ks], bb[n][ks],
                                                        acc[m][nq * 2 + n], 0, 0, 0);
    };

    // prologue: tiles 0,1 in steady order [A0,B0,A1,B1] (6 loads/thread/tile)
    stA(0, 0, 0); stB(0, 0, 0); stA(0, 1, 0); stB(0, 1, 0);
    stA(1, 0, 1); stB(1, 0, 1); stA(1, 1, 1); stB(1, 1, 1);
    vmwait<6>();
    barend();

    int s = 0;
    for (int t = 0; t < NT; ++t) {
      int s2 = s + 2; if (s2 >= 3) s2 -= 3;
      const bool pf = (t + 2 < NT);
      // merged phase: all 16 ds_reads + full next-tile prefetch
      rdA(s); rdB(s, 0, bA); rdB(s, 1, bB);
      if (pf) { stA(s2, 0, t + 2); stB(s2, 0, t + 2); stA(s2, 1, t + 2); stB(s2, 1, t + 2); }
      barmid();
      __builtin_amdgcn_s_setprio(1);
      mm(0, bA); mm(1, bB);
      __builtin_amdgcn_s_setprio(0);
      if (t == NT - 2) vmwait<0>(); else if (t < NT - 2) vmwait<6>();
      barend();
      s = (s + 1 == 3) ? 0 : s + 1;
    }

    const int rb = i0 + wr * 64 + fq * 4;
    const int cb = j0 + wc * 64 + fr;
    const long tb = (long)b * p.sC;
#pragma unroll
    for (int m = 0; m < 4; ++m)
#pragma unroll
      for (int n = 0; n < 4; ++n) {
        const int col = cb + n * 16;
#pragma unroll
        for (int e = 0; e < 4; ++e) {
          const int row = rb + m * 16 + e;
          const float val = acc[m][n][e];
          if constexpr (EPI == 0) {
            ((unsigned short*)p.C)[tb + (long)row * p.ldc + col] = f2b(val);
          } else if constexpr (EPI == 1) {
            ((float*)p.C)[tb + (long)row * p.ldc + col] = val;
          } else if constexpr (EPI == 2) {
            ((unsigned short*)p.C)[tb + (long)row * p.ldc + col] =
                f2b(val / (1.f + __expf(-val)));
          } else {
            const long coff = tb + (long)row * p.ldc + col;
            const float g = b2f(p.gate[coff]);
            const float r = p.rinv[b * p.M + row];
            ((unsigned short*)p.C)[coff] = f2b(val * r * g);
          }
        }
      }
  }
}

// ---------- 2-phase ring-3 GEMM (K=128 score GEMMs) ----------
// EPI: 5=rel-shift scatter  6=exp-fuse
template<int NREP, int EPI>
__launch_bounds__(512, 4)
__global__ void gemm2p_k(GemmP p) {
  constexpr int BN = NREP * 64;
  constexpr int CB = NREP / 2;
  constexpr int LPT = 1 + CB;
  const int lin = (int)blockIdx.x + (((int)blockIdx.y + (int)blockIdx.z * (int)gridDim.y) << p.gxs);
  const int wg = (lin & 7) * p.qchunk + (lin >> 3);
  const int ii = wg & ((1 << p.gxs) - 1);
  const int jj = (wg >> p.gxs) & ((1 << p.gys) - 1);
  const int b  = wg >> (p.gxs + p.gys);
  const int i0 = ii * 128, j0 = jj * BN;
  if (p.causal && j0 > i0 + 127) return;
  const unsigned short* Ag = p.A + (long)b * p.sA + (long)i0 * p.lda;
  const unsigned short* Bg = p.B + (long)b * p.sB + (long)j0 * p.ldb;
  const int NT = p.K >> 5;

  __shared__ unsigned short As[3][128 * 32];
  __shared__ unsigned short Bs[3][BN * 32];

  const int tid = threadIdx.x;
  const int w = tid >> 6, l = tid & 63;
  const int wr = w >> 2, wc = w & 3;
  const int lrow = l >> 2;
  const int swz = ((l & 3) ^ ((l >> 3) & 3)) * 8;

  auto stage = [&](int t, int bi) {
    gload_lds16(Ag + (long)(w * 16 + lrow) * p.lda + t * 32 + swz, &As[bi][w * 512]);
#pragma unroll
    for (int i = 0; i < CB; ++i) {
      const int c = w * CB + i;
      gload_lds16(Bg + (long)(c * 16 + lrow) * p.ldb + t * 32 + swz, &Bs[bi][c * 512]);
    }
  };

  f32x4 acc[4][NREP];
#pragma unroll
  for (int m = 0; m < 4; ++m)
#pragma unroll
    for (int n = 0; n < NREP; ++n) acc[m][n] = (f32x4){0.f, 0.f, 0.f, 0.f};

  const int fr = l & 15, fq = l >> 4;
  const int rg = (fq ^ ((fr >> 1) & 3)) * 8;
  const int aoff = (wr * 64 + fr) * 32 + rg;
  const int boff = (wc * (NREP * 16) + fr) * 32 + rg;

  stage(0, 0);
  if (NT > 1) stage(1, 1);

  int bi = 0;
  for (int t = 0; t < NT; ++t) {
    if (t == NT - 1) vmwait<0>(); else vmwait<LPT>();
    __builtin_amdgcn_s_barrier();
    __builtin_amdgcn_sched_barrier(0);
    const unsigned short* as = &As[bi][0];
    const unsigned short* bs = &Bs[bi][0];
    s16x8 af[4], bf[NREP];
#pragma unroll
    for (int m = 0; m < 4; ++m) af[m] = *(const s16x8*)(as + aoff + m * 512);
#pragma unroll
    for (int n = 0; n < NREP; ++n) bf[n] = *(const s16x8*)(bs + boff + n * 512);
    if (t + 2 < NT) {
      int bi2 = bi + 2; if (bi2 >= 3) bi2 -= 3;
      stage(t + 2, bi2);
    }
    __builtin_amdgcn_s_setprio(1);
#pragma unroll
    for (int m = 0; m < 4; ++m)
#pragma unroll
      for (int n = 0; n < NREP; ++n)
        acc[m][n] = __builtin_amdgcn_mfma_f32_16x16x32_bf16(af[m], bf[n], acc[m][n], 0, 0, 0);
    __builtin_amdgcn_s_setprio(0);
    bi = (bi + 1 == 3) ? 0 : bi + 1;
  }

  const int rbase = i0 + wr * 64 + fq * 4;
  const int cbase = j0 + wc * (NREP * 16) + fr;
  const long tb = (long)b * p.sC;

  if constexpr (EPI == 6) {
    float psum[16];
#pragma unroll
    for (int t = 0; t < 16; ++t) psum[t] = 0.f;
#pragma unroll
    for (int m = 0; m < 4; ++m)
#pragma unroll
      for (int n = 0; n < NREP; ++n) {
        const int col = cbase + n * 16;
#pragma unroll
        for (int e = 0; e < 4; ++e) {
          const int row = rbase + m * 16 + e;
          const long o = tb + (long)row * p.ldc + col;
          float ev = 0.f;
          if (col <= row) {
            const float s = acc[m][n][e] + b2f(p.bds[o]);
            ev = __expf(fminf(s, 60.f));
          }
          ((unsigned short*)p.C)[o] = f2b(ev);
          psum[m * 4 + e] += ev;
        }
      }
#pragma unroll
    for (int t = 0; t < 16; ++t) {
      float v = psum[t];
      v += __shfl_xor(v, 1); v += __shfl_xor(v, 2);
      v += __shfl_xor(v, 4); v += __shfl_xor(v, 8);
      psum[t] = v;
    }
    if (fr == 0) {
#pragma unroll
      for (int t = 0; t < 16; ++t) {
        const int row = rbase + (t >> 2) * 16 + (t & 3);
        p.stats[((long)(b * p.M + row) * 16 + jj) * 4 + wc] = psum[t];
      }
    }
    return;
  }

#pragma unroll
  for (int m = 0; m < 4; ++m)
#pragma unroll
    for (int n = 0; n < NREP; ++n) {
      const int col = cbase + n * 16;
#pragma unroll
      for (int e = 0; e < 4; ++e) {
        const int row = rbase + m * 16 + e;
        if constexpr (EPI == 5) {
          if (col <= row)
            ((unsigned short*)p.C)[tb + (long)row * p.ldc + (row - col)] = f2b(acc[m][n][e]);
        }
      }
    }
}

// ---------- 128x128 GEMM (m97 structure + conflict-free swizzle) ----------
// 16KB LDS -> multi-block/CU implicit overlap (reference: 874-912 TF).
// EPI: 0=bf16  1=fp32  2=silu bf16  3=qu/qv/kk split
template<int EPI>
__launch_bounds__(256)
__global__ void gemm_bt_k(GemmP p) {
  const int i0 = blockIdx.x * 128;
  const int j0 = blockIdx.y * 128;
  const unsigned short* A = p.A + (long)i0 * p.lda;
  const unsigned short* B = p.B + (long)j0 * p.ldb;

  __shared__ unsigned short As[128 * 32];
  __shared__ unsigned short Bs[128 * 32];

  const int tid = threadIdx.x;
  const int w = tid >> 6, l = tid & 63;
  const int wr = w >> 1, wc = w & 1;

  f32x4 acc[4][4];
#pragma unroll
  for (int m = 0; m < 4; ++m)
#pragma unroll
    for (int n = 0; n < 4; ++n) acc[m][n] = (f32x4){0.f, 0.f, 0.f, 0.f};

  const int srow = (l >> 2);
  const int scol = ((l & 3) ^ ((l >> 3) & 3)) * 8;
  const unsigned short* ga0 = A + (long)(w * 16 + srow) * p.lda + scol;
  const unsigned short* ga1 = A + (long)((w + 4) * 16 + srow) * p.lda + scol;
  const unsigned short* gb0 = B + (long)(w * 16 + srow) * p.ldb + scol;
  const unsigned short* gb1 = B + (long)((w + 4) * 16 + srow) * p.ldb + scol;
  unsigned short* la0 = As + w * 512;
  unsigned short* la1 = As + (w + 4) * 512;
  unsigned short* lb0 = Bs + w * 512;
  unsigned short* lb1 = Bs + (w + 4) * 512;

  const int rg = ((l >> 4) ^ (((l & 15) >> 1) & 3)) * 8;
  const unsigned short* ap = As + ((wr * 64) + (l & 15)) * 32 + rg;
  const unsigned short* bp = Bs + ((wc * 64) + (l & 15)) * 32 + rg;

  for (int k0 = 0; k0 < p.K; k0 += 32) {
    gload_lds16(ga0 + k0, la0);
    gload_lds16(ga1 + k0, la1);
    gload_lds16(gb0 + k0, lb0);
    gload_lds16(gb1 + k0, lb1);
    __syncthreads();
    s16x8 af[4], bfr[4];
#pragma unroll
    for (int m = 0; m < 4; ++m) af[m] = *(const s16x8*)(ap + m * 16 * 32);
#pragma unroll
    for (int n = 0; n < 4; ++n) bfr[n] = *(const s16x8*)(bp + n * 16 * 32);
#pragma unroll
    for (int m = 0; m < 4; ++m)
#pragma unroll
      for (int n = 0; n < 4; ++n)
        acc[m][n] = __builtin_amdgcn_mfma_f32_16x16x32_bf16(af[m], bfr[n], acc[m][n], 0, 0, 0);
    __syncthreads();
  }

  const int rbase = i0 + wr * 64 + (l >> 4) * 4;
  const int cbase = j0 + wc * 64 + (l & 15);
#pragma unroll
  for (int m = 0; m < 4; ++m)
#pragma unroll
    for (int n = 0; n < 4; ++n) {
      const int col = cbase + n * 16;
#pragma unroll
      for (int e = 0; e < 4; ++e) {
        const int row = rbase + m * 16 + e;
        const float val = acc[m][n][e];
        if constexpr (EPI == 0) {
          ((unsigned short*)p.C)[(long)row * p.ldc + col] = f2b(val);
        } else if constexpr (EPI == 1) {
          ((float*)p.C)[(long)row * p.ldc + col] = val;
        } else if constexpr (EPI == 2) {
          ((unsigned short*)p.C)[(long)row * p.ldc + col] =
              f2b(val / (1.f + __expf(-val)));
        } else if constexpr (EPI == 3) {
          if (j0 == 0) {
            const float q = val * p.invtau;
            const long o = (long)row * 128 + col;
            ((unsigned short*)p.C)[o] = f2b(q + p.uvec[col]);
            p.qv_out[o] = f2b(q + p.vvec[col]);
          } else {
            p.kk_out[(long)row * 128 + (col - 128)] = f2b(val);
          }
        }
      }
    }
}

// ---------- RMSNorm ----------
__launch_bounds__(256)
__global__ void rmsnorm_k(const float* __restrict__ x, const float* __restrict__ g,
                          unsigned short* __restrict__ xt) {
  const long row = blockIdx.x;
  const float* xr = x + row * 1024;
  const int t = threadIdx.x;
  const float4 v = ((const float4*)xr)[t];
  float ss = v.x * v.x + v.y * v.y + v.z * v.z + v.w * v.w;
#pragma unroll
  for (int o = 1; o < 64; o <<= 1) ss += __shfl_xor(ss, o);
  __shared__ float wsum[4];
  if ((t & 63) == 0) wsum[t >> 6] = ss;
  __syncthreads();
  const float tot = wsum[0] + wsum[1] + wsum[2] + wsum[3];
  const float r = 1.0f / sqrtf(tot * (1.0f / 1024.0f) + 1e-6f);
  const float4 gv = ((const float4*)g)[t];
  u16x4 o;
  o.x = f2b(v.x * r * gv.x); o.y = f2b(v.y * r * gv.y);
  o.z = f2b(v.z * r * gv.z); o.w = f2b(v.w * r * gv.w);
  ((u16x4*)(xt + row * 1024))[t] = o;
}

// ---------- sinusoid table (UNFLIPPED) ----------
__launch_bounds__(256)
__global__ void sinemb_k(unsigned short* __restrict__ emb) {
  const int idx = blockIdx.x * 256 + threadIdx.x;
  const int t = idx >> 10, w = idx & 1023;
  const int h = w & 511;
  const float inv = __expf(-(float)h * (9.2103403719761836f / 512.0f));
  const float pre = (float)t * inv;
  const float val = (w < 512) ? sinf(pre) : cosf(pre);
  emb[idx] = f2b(val);
}

// ---------- fused transpose-cast: all 6 weights in ONE launch ----------
struct TcP {
  const float* in[6];
  unsigned short* out[6];
  int R[6], C[6];
  int start[7];
};
__launch_bounds__(256)
__global__ void transcast6_k(TcP tc) {
  __shared__ float tile[32][33];
  const int bid = blockIdx.x;
  int m = 0;
#pragma unroll
  for (int i = 0; i < 6; ++i) if (bid >= tc.start[i + 1]) m = i + 1;
  const int local = bid - tc.start[m];
  const int R = tc.R[m], C = tc.C[m];
  const int tc_c = C >> 5;
  const int cx = local % tc_c, ry = local / tc_c;
  const int c0 = cx * 32, r0 = ry * 32;
  const float* in = tc.in[m];
  unsigned short* out = tc.out[m];
  const int tx = threadIdx.x & 31, ty = threadIdx.x >> 5;
#pragma unroll
  for (int k = 0; k < 4; ++k)
    tile[ty + k * 8][tx] = in[(long)(r0 + ty + k * 8) * C + c0 + tx];
  __syncthreads();
#pragma unroll
  for (int k = 0; k < 4; ++k)
    out[(long)(c0 + ty + k * 8) * R + r0 + tx] = f2b(tile[tx][ty + k * 8]);
}

// ---------- per-row 1/sum over stats[BT][16 jt][4 wc] ----------
__global__ void rowinv_k(const float* __restrict__ stats, float* __restrict__ rinv,
                         int T, int BT) {
  const int idx = blockIdx.x * 256 + threadIdx.x;
  if (idx >= BT) return;
  const int i = idx & (T - 1);
  const int nt = (i >> 8) + 1;
  const float* st = stats + (long)idx * 64;
  float s = 0.f;
  for (int jt = 0; jt < nt; ++jt)
    s += st[jt * 4] + st[jt * 4 + 1] + st[jt * 4 + 2] + st[jt * 4 + 3];
  rinv[idx] = 1.0f / s;
}

// ---------- host ----------
extern "C" void kernel_launch(void* const* d_in, const int* in_sizes, int n_in,
                              void* d_out, int out_size, void* d_ws, size_t ws_size,
                              hipStream_t stream) {
  const float* x    = (const float*)d_in[0];
  const float* g_ln = (const float*)d_in[1];
  const float* W_q  = (const float*)d_in[2];
  const float* W_k  = (const float*)d_in[3];
  const float* W_v  = (const float*)d_in[4];
  const float* W_g  = (const float*)d_in[5];
  const float* W_r  = (const float*)d_in[6];
  const float* xl_u = (const float*)d_in[7];
  const float* xl_v = (const float*)d_in[8];
  const float* W_o  = (const float*)d_in[9];
  float* out = (float*)d_out;

  const int B = 2, T = 4096, D = 1024, K = 128, V = 2048;
  const int BT = B * T;

  char* ws = (char*)d_ws;
  size_t off = 0;
  auto alloc = [&](size_t bytes) -> void* {
    void* p = ws + off; off += (bytes + 255) & ~(size_t)255; return p;
  };
  unsigned short* XT   = (unsigned short*)alloc((size_t)BT * D * 2);
  unsigned short* WQKT = (unsigned short*)alloc((size_t)256 * D * 2);
  unsigned short* WVT  = (unsigned short*)alloc((size_t)V * D * 2);
  unsigned short* WGT  = (unsigned short*)alloc((size_t)V * D * 2);
  unsigned short* WRT  = (unsigned short*)alloc((size_t)K * D * 2);
  unsigned short* WOT  = (unsigned short*)alloc((size_t)D * V * 2);
  unsigned short* QU   = (unsigned short*)alloc((size_t)BT * K * 2);
  unsigned short* QV   = (unsigned short*)alloc((size_t)BT * K * 2);
  unsigned short* KKb  = (unsigned short*)alloc((size_t)BT * K * 2);
  unsigned short* RR   = (unsigned short*)alloc((size_t)T * K * 2);
  unsigned short* VVT  = (unsigned short*)alloc((size_t)V * BT * 2);
  unsigned short* GATE = (unsigned short*)alloc((size_t)BT * V * 2);
  float* STATS         = (float*)alloc((size_t)BT * 64 * 4);
  float* RINV          = (float*)alloc((size_t)BT * 4);
  unsigned short* EBUF = (unsigned short*)alloc((size_t)B * T * T * 2);
  unsigned short* BD2  = (unsigned short*)alloc((size_t)B * T * T * 2);
  unsigned short* EMB  = BD2;  // [T,D] bf16, dead before BD2 is written
  unsigned short* WVG  = BD2;  // [BT,V] bf16, written after BD2 is consumed
  if (off > ws_size) return;
  (void)in_sizes; (void)n_in; (void)out_size;

  const float invtau = 0.08838834764831845f;  // 1/sqrt(128)

  { // all 6 weight transposes in one launch
    TcP tc{};
    const float* ins[6]  = {W_q, W_k, W_v, W_g, W_r, W_o};
    unsigned short* os[6] = {WQKT, WQKT + (size_t)K * D, WVT, WGT, WRT, WOT};
    const int Rs[6] = {D, D, D, D, D, V};
    const int Cs[6] = {K, K, V, V, K, D};
    int acc = 0;
    for (int i = 0; i < 6; ++i) {
      tc.in[i] = ins[i]; tc.out[i] = os[i]; tc.R[i] = Rs[i]; tc.C[i] = Cs[i];
      tc.start[i] = acc; acc += (Rs[i] / 32) * (Cs[i] / 32);
    }
    tc.start[6] = acc;
    transcast6_k<<<acc, 256, 0, stream>>>(tc);
  }
  rmsnorm_k<<<BT, 256, 0, stream>>>(x, g_ln, XT);
  sinemb_k<<<(T * D) / 256, 256, 0, stream>>>(EMB);

  { // qu/qv/k fused  (m97 engine)
    GemmP p{}; p.A = XT; p.B = WQKT; p.C = QU;
    p.M = BT; p.N = 256; p.K = D; p.lda = D; p.ldb = D; p.ldc = K;
    p.uvec = xl_u; p.vvec = xl_v; p.qv_out = QV; p.kk_out = KKb; p.invtau = invtau;
    gemm_bt_k<3><<<dim3(BT / 128, 2, 1), 256, 0, stream>>>(p);
  }
  { // rr = sin_noflip @ W_r  (m97 engine)
    GemmP p{}; p.A = EMB; p.B = WRT; p.C = RR;
    p.M = T; p.N = K; p.K = D; p.lda = D; p.ldb = D; p.ldc = K;
    gemm_bt_k<0><<<dim3(T / 128, 1, 1), 256, 0, stream>>>(p);
  }
  { // v^T: A=WVT[2048,1024], B=XT[8192,1024] -> VVT[2048,8192]  (m97 engine, 1024 blocks)
    GemmP p{}; p.A = WVT; p.B = XT; p.C = VVT;
    p.M = V; p.N = BT; p.K = D; p.lda = D; p.ldb = D; p.ldc = BT;
    gemm_bt_k<0><<<dim3(V / 128, BT / 128, 1), 256, 0, stream>>>(p);
  }
  { // gate = silu(x~ @ W_g)  (m97 engine, 1024 blocks)
    GemmP p{}; p.A = XT; p.B = WGT; p.C = GATE;
    p.M = BT; p.N = V; p.K = D; p.lda = D; p.ldb = D; p.ldc = V;
    gemm_bt_k<2><<<dim3(BT / 128, V / 128, 1), 256, 0, stream>>>(p);
  }
  { // BD rel-shifted: scores_bd[b,i,i-d] = (qv . rr^T)[b,i,d]
    GemmP p{}; p.A = QV; p.B = RR; p.C = BD2;
    p.sA = (long)T * K; p.sB = 0; p.sC = (long)T * T;
    p.M = T; p.N = T; p.K = K; p.lda = K; p.ldb = K; p.ldc = T; p.causal = 1;
    p.gxs = 5; p.gys = 4; p.qchunk = 128;
    gemm2p_k<4, 5><<<dim3(32, 16, B), 512, 0, stream>>>(p);
  }
  { // E = exp(min(qu.k^T + BDs, 60)) causal-masked; per-(row,tile,wave) sums
    GemmP p{}; p.A = QU; p.B = KKb; p.C = EBUF;
    p.sA = (long)T * K; p.sB = (long)T * K; p.sC = (long)T * T;
    p.M = T; p.N = T; p.K = K; p.lda = K; p.ldb = K; p.ldc = T; p.causal = 1;
    p.bds = BD2; p.stats = STATS;
    p.gxs = 5; p.gys = 4; p.qchunk = 128;
    gemm2p_k<4, 6><<<dim3(32, 16, B), 512, 0, stream>>>(p);
  }
  rowinv_k<<<BT / 256, 256, 0, stream>>>(STATS, RINV, T, BT);
  { // wv = (E @ v) * rinv * gate  (merged 8p128, paired causal balance)
    GemmP p{}; p.A = EBUF; p.B = VVT; p.C = WVG;
    p.sA = (long)T * T; p.sB = T; p.sC = (long)T * V;
    p.M = T; p.N = V; p.K = T; p.lda = T; p.ldb = BT; p.ldc = V;
    p.kend_mode = 1; p.rinv = RINV; p.gate = GATE;
    p.gxs = 3; p.gys = 4; p.qchunk = 32;
    gemm8p128_k<1, 4><<<dim3(8, 16, 2), 512, 0, stream>>>(p);
  }
  { // res = wvg @ W_o -> fp32 out  (m97 engine, 512 blocks)
    GemmP p{}; p.A = WVG; p.B = WOT; p.C = out;
    p.M = BT; p.N = D; p.K = V; p.lda = V; p.ldb = V; p.ldc = D;
    gemm_bt_k<1><<<dim3(BT / 128, D / 128, 1), 256, 0, stream>>>(p);
  }
}

// Round 14
// 388.254 us; speedup vs baseline: 1.0685x; 1.0685x over previous
//
#include <hip/hip_runtime.h>
#include <hip/hip_bf16.h>
#include <stdint.h>

// ---------- types & helpers ----------
typedef __attribute__((ext_vector_type(4))) float f32x4;
typedef __attribute__((ext_vector_type(8))) short s16x8;      // MFMA bf16 frag (8 bf16)
typedef __attribute__((ext_vector_type(8))) unsigned short u16x8;
typedef __attribute__((ext_vector_type(4))) unsigned short u16x4;

static __device__ __forceinline__ float b2f(unsigned short u) {
  union { unsigned int i; float f; } v; v.i = ((unsigned int)u) << 16; return v.f;
}
static __device__ __forceinline__ unsigned short f2b(float f) {
  unsigned int x = __float_as_uint(f);
  return (unsigned short)((x + 0x7fffu + ((x >> 16) & 1u)) >> 16);  // RNE
}

typedef __attribute__((address_space(1))) const void gconst_t;
typedef __attribute__((address_space(3))) void lds_t;
static __device__ __forceinline__ void gload_lds16(const void* g, void* l) {
  __builtin_amdgcn_global_load_lds((gconst_t*)g, (lds_t*)l, 16, 0, 0);
}

template<int N>
static __device__ __forceinline__ void vmwait() {
  asm volatile("s_waitcnt vmcnt(%0)" :: "n"(N) : "memory");
}
static __device__ __forceinline__ void barmid() {
  __builtin_amdgcn_sched_barrier(0);
  __builtin_amdgcn_s_barrier();
  asm volatile("s_waitcnt lgkmcnt(0)" ::: "memory");
  __builtin_amdgcn_sched_barrier(0);
}
static __device__ __forceinline__ void barend() {
  __builtin_amdgcn_sched_barrier(0);
  __builtin_amdgcn_s_barrier();
}

struct GemmP {
  const unsigned short* A; const unsigned short* B; void* C;
  long sA, sB, sC;                 // batch strides (elements)
  int M, N, K, lda, ldb, ldc;
  int causal, kend_mode, swapxy;
  int gxs, gys, qchunk;            // log2 decode of wg, nwg/8
  const float* uvec; const float* vvec;
  unsigned short* qv_out; unsigned short* kk_out; float invtau;
  const float* rinv; const unsigned short* gate;
  const unsigned short* bds; float* stats;
};

// ---------- ring-3 256x128 GEMM (merged single-barrier K-loop) ----------
// Main dense/causal engine: measured 1.2x faster per FLOP than the 8p256
// schedule (wv A/B, R10 vs R11) and faster than the m97 128^2 engine (R13).
// 8 waves (4M x 2N), per-wave C 64x64. LDS 3 slots x {A0,A1,B} = 144KB.
// One {16 ds_read + prefetch -> barrier+lgkm0 -> 32 MFMA -> counted vmcnt ->
// barrier} per K-tile of 64. vmcnt(6) = one tile in flight. PAIR=1: block
// runs M-tiles (15-xx) then (xx) — causal kends sum constant.
// EPI: 0=bf16  1=fp32  2=silu bf16  4=wv(*rinv*gate)
template<int PAIR, int EPI>
__launch_bounds__(512, 2)
__global__ void gemm8p128_k(GemmP p) {
  __shared__ unsigned short L[3][3][8192];   // [slot][A0,A1,B][128*64]
  const int lin = (int)blockIdx.x + (int)gridDim.x * ((int)blockIdx.y + (int)gridDim.y * (int)blockIdx.z);
  const int wg = (lin & 7) * p.qchunk + (lin >> 3);
  const int xx = wg & ((1 << p.gxs) - 1);
  const int yy = (wg >> p.gxs) & ((1 << p.gys) - 1);
  const int b  = wg >> (p.gxs + p.gys);
  const int jj = PAIR ? yy : (p.swapxy ? xx : yy);
  const int j0 = jj * 128;
  const unsigned short* Bg0 = p.B + (long)b * p.sB + (long)j0 * p.ldb;
  const int lda = p.lda, ldb = p.ldb;

  const int tid = threadIdx.x;
  const int w = tid >> 6, l = tid & 63;
  const int wr = w >> 1, wc = w & 1;
  const int fr = l & 15, fq = l >> 4;

  const int sx = (fr & 7) << 4;        // 3-bit row XOR (granule bits 4-6)
  const int abase = ((((wr & 1) << 13) + (fr << 7) + (fq << 4))) ^ sx;
  const int bbase = (((wc << 13) + (fr << 7) + (fq << 4))) ^ sx;

  const int passes = PAIR ? 2 : 1;
  for (int ps = 0; ps < passes; ++ps) {
    const int ii = PAIR ? (ps ? xx : (15 - xx)) : (p.swapxy ? yy : xx);
    const int i0 = ii * 256;
    const unsigned short* Ag = p.A + (long)b * p.sA + (long)i0 * lda;
    const int kend = p.kend_mode ? min(p.K, i0 + 256) : p.K;
    const int NT = kend >> 6;

    auto stA = [&](int slot, int h, int t) {
#pragma unroll
      for (int u = 0; u < 2; ++u) {
        const int sl = u * 512 + tid, r = sl >> 3, g = sl & 7;
        const int gs = g ^ (r & 7);
        gload_lds16(Ag + (long)(h * 128 + r) * lda + t * 64 + gs * 8, &L[slot][h][sl * 8]);
      }
    };
    auto stB = [&](int slot, int bh, int t) {
      const int r = tid >> 3, g = tid & 7;
      const int rloc = bh * 64 + r;
      const int gs = g ^ (rloc & 7);
      gload_lds16(Bg0 + (long)rloc * ldb + t * 64 + gs * 8, &L[slot][2][bh * 4096 + tid * 8]);
    };

    f32x4 acc[4][4];
#pragma unroll
    for (int m = 0; m < 4; ++m)
#pragma unroll
      for (int n = 0; n < 4; ++n) acc[m][n] = (f32x4){0.f, 0.f, 0.f, 0.f};
    s16x8 a[4][2], bA[2][2], bB[2][2];

    auto rdA = [&](int slot) {
      const int reg = wr >> 1;
#pragma unroll
      for (int m = 0; m < 4; ++m)
#pragma unroll
        for (int ks = 0; ks < 2; ++ks)
          a[m][ks] = *(const s16x8*)((const char*)&L[slot][reg][0] +
                                     ((abase ^ (ks << 6)) | (m << 11)));
    };
    auto rdB = [&](int slot, int nq, s16x8 (&bb)[2][2]) {
#pragma unroll
      for (int n = 0; n < 2; ++n)
#pragma unroll
        for (int ks = 0; ks < 2; ++ks)
          bb[n][ks] = *(const s16x8*)((const char*)&L[slot][2][0] +
                                      ((bbase ^ (ks << 6)) | ((nq * 2 + n) << 11)));
    };
    auto mm = [&](int nq, s16x8 (&bb)[2][2]) {
#pragma unroll
      for (int m = 0; m < 4; ++m)
#pragma unroll
        for (int n = 0; n < 2; ++n)
#pragma unroll
          for (int ks = 0; ks < 2; ++ks)
            acc[m][nq * 2 + n] =
                __builtin_amdgcn_mfma_f32_16x16x32_bf16(a[m][ks], bb[n][ks],
                                                        acc[m][nq * 2 + n], 0, 0, 0);
    };

    // prologue: tiles 0,1 in steady order [A0,B0,A1,B1] (6 loads/thread/tile)
    stA(0, 0, 0); stB(0, 0, 0); stA(0, 1, 0); stB(0, 1, 0);
    stA(1, 0, 1); stB(1, 0, 1); stA(1, 1, 1); stB(1, 1, 1);
    vmwait<6>();
    barend();

    int s = 0;
    for (int t = 0; t < NT; ++t) {
      int s2 = s + 2; if (s2 >= 3) s2 -= 3;
      const bool pf = (t + 2 < NT);
      // merged phase: all 16 ds_reads + full next-tile prefetch
      rdA(s); rdB(s, 0, bA); rdB(s, 1, bB);
      if (pf) { stA(s2, 0, t + 2); stB(s2, 0, t + 2); stA(s2, 1, t + 2); stB(s2, 1, t + 2); }
      barmid();
      __builtin_amdgcn_s_setprio(1);
      mm(0, bA); mm(1, bB);
      __builtin_amdgcn_s_setprio(0);
      if (t == NT - 2) vmwait<0>(); else if (t < NT - 2) vmwait<6>();
      barend();
      s = (s + 1 == 3) ? 0 : s + 1;
    }

    const int rb = i0 + wr * 64 + fq * 4;
    const int cb = j0 + wc * 64 + fr;
    const long tb = (long)b * p.sC;
#pragma unroll
    for (int m = 0; m < 4; ++m)
#pragma unroll
      for (int n = 0; n < 4; ++n) {
        const int col = cb + n * 16;
#pragma unroll
        for (int e = 0; e < 4; ++e) {
          const int row = rb + m * 16 + e;
          const float val = acc[m][n][e];
          if constexpr (EPI == 0) {
            ((unsigned short*)p.C)[tb + (long)row * p.ldc + col] = f2b(val);
          } else if constexpr (EPI == 1) {
            ((float*)p.C)[tb + (long)row * p.ldc + col] = val;
          } else if constexpr (EPI == 2) {
            ((unsigned short*)p.C)[tb + (long)row * p.ldc + col] =
                f2b(val / (1.f + __expf(-val)));
          } else {
            const long coff = tb + (long)row * p.ldc + col;
            const float g = b2f(p.gate[coff]);
            const float r = p.rinv[b * p.M + row];
            ((unsigned short*)p.C)[coff] = f2b(val * r * g);
          }
        }
      }
  }
}

// ---------- 2-phase ring-3 GEMM (K=128 score GEMMs) ----------
// EPI: 5=rel-shift scatter  6=exp-fuse
template<int NREP, int EPI>
__launch_bounds__(512, 4)
__global__ void gemm2p_k(GemmP p) {
  constexpr int BN = NREP * 64;
  constexpr int CB = NREP / 2;
  constexpr int LPT = 1 + CB;
  const int lin = (int)blockIdx.x + (((int)blockIdx.y + (int)blockIdx.z * (int)gridDim.y) << p.gxs);
  const int wg = (lin & 7) * p.qchunk + (lin >> 3);
  const int ii = wg & ((1 << p.gxs) - 1);
  const int jj = (wg >> p.gxs) & ((1 << p.gys) - 1);
  const int b  = wg >> (p.gxs + p.gys);
  const int i0 = ii * 128, j0 = jj * BN;
  if (p.causal && j0 > i0 + 127) return;
  const unsigned short* Ag = p.A + (long)b * p.sA + (long)i0 * p.lda;
  const unsigned short* Bg = p.B + (long)b * p.sB + (long)j0 * p.ldb;
  const int NT = p.K >> 5;

  __shared__ unsigned short As[3][128 * 32];
  __shared__ unsigned short Bs[3][BN * 32];

  const int tid = threadIdx.x;
  const int w = tid >> 6, l = tid & 63;
  const int wr = w >> 2, wc = w & 3;
  const int lrow = l >> 2;
  const int swz = ((l & 3) ^ ((l >> 3) & 3)) * 8;

  auto stage = [&](int t, int bi) {
    gload_lds16(Ag + (long)(w * 16 + lrow) * p.lda + t * 32 + swz, &As[bi][w * 512]);
#pragma unroll
    for (int i = 0; i < CB; ++i) {
      const int c = w * CB + i;
      gload_lds16(Bg + (long)(c * 16 + lrow) * p.ldb + t * 32 + swz, &Bs[bi][c * 512]);
    }
  };

  f32x4 acc[4][NREP];
#pragma unroll
  for (int m = 0; m < 4; ++m)
#pragma unroll
    for (int n = 0; n < NREP; ++n) acc[m][n] = (f32x4){0.f, 0.f, 0.f, 0.f};

  const int fr = l & 15, fq = l >> 4;
  const int rg = (fq ^ ((fr >> 1) & 3)) * 8;
  const int aoff = (wr * 64 + fr) * 32 + rg;
  const int boff = (wc * (NREP * 16) + fr) * 32 + rg;

  stage(0, 0);
  if (NT > 1) stage(1, 1);

  int bi = 0;
  for (int t = 0; t < NT; ++t) {
    if (t == NT - 1) vmwait<0>(); else vmwait<LPT>();
    __builtin_amdgcn_s_barrier();
    __builtin_amdgcn_sched_barrier(0);
    const unsigned short* as = &As[bi][0];
    const unsigned short* bs = &Bs[bi][0];
    s16x8 af[4], bf[NREP];
#pragma unroll
    for (int m = 0; m < 4; ++m) af[m] = *(const s16x8*)(as + aoff + m * 512);
#pragma unroll
    for (int n = 0; n < NREP; ++n) bf[n] = *(const s16x8*)(bs + boff + n * 512);
    if (t + 2 < NT) {
      int bi2 = bi + 2; if (bi2 >= 3) bi2 -= 3;
      stage(t + 2, bi2);
    }
    __builtin_amdgcn_s_setprio(1);
#pragma unroll
    for (int m = 0; m < 4; ++m)
#pragma unroll
      for (int n = 0; n < NREP; ++n)
        acc[m][n] = __builtin_amdgcn_mfma_f32_16x16x32_bf16(af[m], bf[n], acc[m][n], 0, 0, 0);
    __builtin_amdgcn_s_setprio(0);
    bi = (bi + 1 == 3) ? 0 : bi + 1;
  }

  const int rbase = i0 + wr * 64 + fq * 4;
  const int cbase = j0 + wc * (NREP * 16) + fr;
  const long tb = (long)b * p.sC;

  if constexpr (EPI == 6) {
    float psum[16];
#pragma unroll
    for (int t = 0; t < 16; ++t) psum[t] = 0.f;
#pragma unroll
    for (int m = 0; m < 4; ++m)
#pragma unroll
      for (int n = 0; n < NREP; ++n) {
        const int col = cbase + n * 16;
#pragma unroll
        for (int e = 0; e < 4; ++e) {
          const int row = rbase + m * 16 + e;
          const long o = tb + (long)row * p.ldc + col;
          float ev = 0.f;
          if (col <= row) {
            const float s = acc[m][n][e] + b2f(p.bds[o]);
            ev = __expf(fminf(s, 60.f));
          }
          ((unsigned short*)p.C)[o] = f2b(ev);
          psum[m * 4 + e] += ev;
        }
      }
#pragma unroll
    for (int t = 0; t < 16; ++t) {
      float v = psum[t];
      v += __shfl_xor(v, 1); v += __shfl_xor(v, 2);
      v += __shfl_xor(v, 4); v += __shfl_xor(v, 8);
      psum[t] = v;
    }
    if (fr == 0) {
#pragma unroll
      for (int t = 0; t < 16; ++t) {
        const int row = rbase + (t >> 2) * 16 + (t & 3);
        p.stats[((long)(b * p.M + row) * 16 + jj) * 4 + wc] = psum[t];
      }
    }
    return;
  }

#pragma unroll
  for (int m = 0; m < 4; ++m)
#pragma unroll
    for (int n = 0; n < NREP; ++n) {
      const int col = cbase + n * 16;
#pragma unroll
      for (int e = 0; e < 4; ++e) {
        const int row = rbase + m * 16 + e;
        if constexpr (EPI == 5) {
          if (col <= row)
            ((unsigned short*)p.C)[tb + (long)row * p.ldc + (row - col)] = f2b(acc[m][n][e]);
        }
      }
    }
}

// ---------- 128x128 GEMM (m97 structure) for small-N GEMMs ----------
template<int EPI>
__launch_bounds__(256)
__global__ void gemm_bt_k(GemmP p) {
  const int i0 = blockIdx.x * 128;
  const int j0 = blockIdx.y * 128;
  const unsigned short* A = p.A + (long)i0 * p.lda;
  const unsigned short* B = p.B + (long)j0 * p.ldb;

  __shared__ unsigned short As[128 * 32];
  __shared__ unsigned short Bs[128 * 32];

  const int tid = threadIdx.x;
  const int w = tid >> 6, l = tid & 63;
  const int wr = w >> 1, wc = w & 1;

  f32x4 acc[4][4];
#pragma unroll
  for (int m = 0; m < 4; ++m)
#pragma unroll
    for (int n = 0; n < 4; ++n) acc[m][n] = (f32x4){0.f, 0.f, 0.f, 0.f};

  const int srow = (l >> 2);
  const int scol = ((l & 3) ^ ((l >> 3) & 3)) * 8;
  const unsigned short* ga0 = A + (long)(w * 16 + srow) * p.lda + scol;
  const unsigned short* ga1 = A + (long)((w + 4) * 16 + srow) * p.lda + scol;
  const unsigned short* gb0 = B + (long)(w * 16 + srow) * p.ldb + scol;
  const unsigned short* gb1 = B + (long)((w + 4) * 16 + srow) * p.ldb + scol;
  unsigned short* la0 = As + w * 512;
  unsigned short* la1 = As + (w + 4) * 512;
  unsigned short* lb0 = Bs + w * 512;
  unsigned short* lb1 = Bs + (w + 4) * 512;

  const int rg = ((l >> 4) ^ (((l & 15) >> 1) & 3)) * 8;
  const unsigned short* ap = As + ((wr * 64) + (l & 15)) * 32 + rg;
  const unsigned short* bp = Bs + ((wc * 64) + (l & 15)) * 32 + rg;

  for (int k0 = 0; k0 < p.K; k0 += 32) {
    gload_lds16(ga0 + k0, la0);
    gload_lds16(ga1 + k0, la1);
    gload_lds16(gb0 + k0, lb0);
    gload_lds16(gb1 + k0, lb1);
    __syncthreads();
    s16x8 af[4], bfr[4];
#pragma unroll
    for (int m = 0; m < 4; ++m) af[m] = *(const s16x8*)(ap + m * 16 * 32);
#pragma unroll
    for (int n = 0; n < 4; ++n) bfr[n] = *(const s16x8*)(bp + n * 16 * 32);
#pragma unroll
    for (int m = 0; m < 4; ++m)
#pragma unroll
      for (int n = 0; n < 4; ++n)
        acc[m][n] = __builtin_amdgcn_mfma_f32_16x16x32_bf16(af[m], bfr[n], acc[m][n], 0, 0, 0);
    __syncthreads();
  }

  const int rbase = i0 + wr * 64 + (l >> 4) * 4;
  const int cbase = j0 + wc * 64 + (l & 15);
#pragma unroll
  for (int m = 0; m < 4; ++m)
#pragma unroll
    for (int n = 0; n < 4; ++n) {
      const int col = cbase + n * 16;
#pragma unroll
      for (int e = 0; e < 4; ++e) {
        const int row = rbase + m * 16 + e;
        const float val = acc[m][n][e];
        if constexpr (EPI == 0) {
          ((unsigned short*)p.C)[(long)row * p.ldc + col] = f2b(val);
        } else if constexpr (EPI == 3) {
          if (j0 == 0) {
            const float q = val * p.invtau;
            const long o = (long)row * 128 + col;
            ((unsigned short*)p.C)[o] = f2b(q + p.uvec[col]);
            p.qv_out[o] = f2b(q + p.vvec[col]);
          } else {
            p.kk_out[(long)row * 128 + (col - 128)] = f2b(val);
          }
        }
      }
    }
}

// ---------- RMSNorm ----------
__launch_bounds__(256)
__global__ void rmsnorm_k(const float* __restrict__ x, const float* __restrict__ g,
                          unsigned short* __restrict__ xt) {
  const long row = blockIdx.x;
  const float* xr = x + row * 1024;
  const int t = threadIdx.x;
  const float4 v = ((const float4*)xr)[t];
  float ss = v.x * v.x + v.y * v.y + v.z * v.z + v.w * v.w;
#pragma unroll
  for (int o = 1; o < 64; o <<= 1) ss += __shfl_xor(ss, o);
  __shared__ float wsum[4];
  if ((t & 63) == 0) wsum[t >> 6] = ss;
  __syncthreads();
  const float tot = wsum[0] + wsum[1] + wsum[2] + wsum[3];
  const float r = 1.0f / sqrtf(tot * (1.0f / 1024.0f) + 1e-6f);
  const float4 gv = ((const float4*)g)[t];
  u16x4 o;
  o.x = f2b(v.x * r * gv.x); o.y = f2b(v.y * r * gv.y);
  o.z = f2b(v.z * r * gv.z); o.w = f2b(v.w * r * gv.w);
  ((u16x4*)(xt + row * 1024))[t] = o;
}

// ---------- sinusoid table (UNFLIPPED) ----------
__launch_bounds__(256)
__global__ void sinemb_k(unsigned short* __restrict__ emb) {
  const int idx = blockIdx.x * 256 + threadIdx.x;
  const int t = idx >> 10, w = idx & 1023;
  const int h = w & 511;
  const float inv = __expf(-(float)h * (9.2103403719761836f / 512.0f));
  const float pre = (float)t * inv;
  const float val = (w < 512) ? sinf(pre) : cosf(pre);
  emb[idx] = f2b(val);
}

// ---------- fused transpose-cast: all 6 weights in ONE launch ----------
struct TcP {
  const float* in[6];
  unsigned short* out[6];
  int R[6], C[6];
  int start[7];
};
__launch_bounds__(256)
__global__ void transcast6_k(TcP tc) {
  __shared__ float tile[32][33];
  const int bid = blockIdx.x;
  int m = 0;
#pragma unroll
  for (int i = 0; i < 6; ++i) if (bid >= tc.start[i + 1]) m = i + 1;
  const int local = bid - tc.start[m];
  const int R = tc.R[m], C = tc.C[m];
  const int tc_c = C >> 5;
  const int cx = local % tc_c, ry = local / tc_c;
  const int c0 = cx * 32, r0 = ry * 32;
  const float* in = tc.in[m];
  unsigned short* out = tc.out[m];
  const int tx = threadIdx.x & 31, ty = threadIdx.x >> 5;
#pragma unroll
  for (int k = 0; k < 4; ++k)
    tile[ty + k * 8][tx] = in[(long)(r0 + ty + k * 8) * C + c0 + tx];
  __syncthreads();
#pragma unroll
  for (int k = 0; k < 4; ++k)
    out[(long)(c0 + ty + k * 8) * R + r0 + tx] = f2b(tile[tx][ty + k * 8]);
}

// ---------- per-row 1/sum over stats[BT][16 jt][4 wc] ----------
__global__ void rowinv_k(const float* __restrict__ stats, float* __restrict__ rinv,
                         int T, int BT) {
  const int idx = blockIdx.x * 256 + threadIdx.x;
  if (idx >= BT) return;
  const int i = idx & (T - 1);
  const int nt = (i >> 8) + 1;
  const float* st = stats + (long)idx * 64;
  float s = 0.f;
  for (int jt = 0; jt < nt; ++jt)
    s += st[jt * 4] + st[jt * 4 + 1] + st[jt * 4 + 2] + st[jt * 4 + 3];
  rinv[idx] = 1.0f / s;
}

// ---------- host ----------
extern "C" void kernel_launch(void* const* d_in, const int* in_sizes, int n_in,
                              void* d_out, int out_size, void* d_ws, size_t ws_size,
                              hipStream_t stream) {
  const float* x    = (const float*)d_in[0];
  const float* g_ln = (const float*)d_in[1];
  const float* W_q  = (const float*)d_in[2];
  const float* W_k  = (const float*)d_in[3];
  const float* W_v  = (const float*)d_in[4];
  const float* W_g  = (const float*)d_in[5];
  const float* W_r  = (const float*)d_in[6];
  const float* xl_u = (const float*)d_in[7];
  const float* xl_v = (const float*)d_in[8];
  const float* W_o  = (const float*)d_in[9];
  float* out = (float*)d_out;

  const int B = 2, T = 4096, D = 1024, K = 128, V = 2048;
  const int BT = B * T;

  char* ws = (char*)d_ws;
  size_t off = 0;
  auto alloc = [&](size_t bytes) -> void* {
    void* p = ws + off; off += (bytes + 255) & ~(size_t)255; return p;
  };
  unsigned short* XT   = (unsigned short*)alloc((size_t)BT * D * 2);
  unsigned short* WQKT = (unsigned short*)alloc((size_t)256 * D * 2);
  unsigned short* WVT  = (unsigned short*)alloc((size_t)V * D * 2);
  unsigned short* WGT  = (unsigned short*)alloc((size_t)V * D * 2);
  unsigned short* WRT  = (unsigned short*)alloc((size_t)K * D * 2);
  unsigned short* WOT  = (unsigned short*)alloc((size_t)D * V * 2);
  unsigned short* QU   = (unsigned short*)alloc((size_t)BT * K * 2);
  unsigned short* QV   = (unsigned short*)alloc((size_t)BT * K * 2);
  unsigned short* KKb  = (unsigned short*)alloc((size_t)BT * K * 2);
  unsigned short* RR   = (unsigned short*)alloc((size_t)T * K * 2);
  unsigned short* VVT  = (unsigned short*)alloc((size_t)V * BT * 2);
  unsigned short* GATE = (unsigned short*)alloc((size_t)BT * V * 2);
  float* STATS         = (float*)alloc((size_t)BT * 64 * 4);
  float* RINV          = (float*)alloc((size_t)BT * 4);
  unsigned short* EBUF = (unsigned short*)alloc((size_t)B * T * T * 2);
  unsigned short* BD2  = (unsigned short*)alloc((size_t)B * T * T * 2);
  unsigned short* EMB  = BD2;  // [T,D] bf16, dead before BD2 is written
  unsigned short* WVG  = BD2;  // [BT,V] bf16, written after BD2 is consumed
  if (off > ws_size) return;
  (void)in_sizes; (void)n_in; (void)out_size;

  const float invtau = 0.08838834764831845f;  // 1/sqrt(128)

  { // all 6 weight transposes in one launch
    TcP tc{};
    const float* ins[6]  = {W_q, W_k, W_v, W_g, W_r, W_o};
    unsigned short* os[6] = {WQKT, WQKT + (size_t)K * D, WVT, WGT, WRT, WOT};
    const int Rs[6] = {D, D, D, D, D, V};
    const int Cs[6] = {K, K, V, V, K, D};
    int acc = 0;
    for (int i = 0; i < 6; ++i) {
      tc.in[i] = ins[i]; tc.out[i] = os[i]; tc.R[i] = Rs[i]; tc.C[i] = Cs[i];
      tc.start[i] = acc; acc += (Rs[i] / 32) * (Cs[i] / 32);
    }
    tc.start[6] = acc;
    transcast6_k<<<acc, 256, 0, stream>>>(tc);
  }
  rmsnorm_k<<<BT, 256, 0, stream>>>(x, g_ln, XT);
  sinemb_k<<<(T * D) / 256, 256, 0, stream>>>(EMB);

  { // qu/qv/k fused
    GemmP p{}; p.A = XT; p.B = WQKT; p.C = QU;
    p.M = BT; p.N = 256; p.K = D; p.lda = D; p.ldb = D; p.ldc = K;
    p.uvec = xl_u; p.vvec = xl_v; p.qv_out = QV; p.kk_out = KKb; p.invtau = invtau;
    gemm_bt_k<3><<<dim3(BT / 128, 2, 1), 256, 0, stream>>>(p);
  }
  { // rr = sin_noflip @ W_r
    GemmP p{}; p.A = EMB; p.B = WRT; p.C = RR;
    p.M = T; p.N = K; p.K = D; p.lda = D; p.ldb = D; p.ldc = K;
    gemm_bt_k<0><<<dim3(T / 128, 1, 1), 256, 0, stream>>>(p);
  }
  { // v^T: A=WVT[2048,1024], B=XT[8192,1024] -> VVT[2048,8192]  (8p128 engine)
    GemmP p{}; p.A = WVT; p.B = XT; p.C = VVT;
    p.M = V; p.N = BT; p.K = D; p.lda = D; p.ldb = D; p.ldc = BT;
    p.gxs = 3; p.gys = 6; p.qchunk = 64; p.swapxy = 0;
    gemm8p128_k<0, 0><<<dim3(8, 64, 1), 512, 0, stream>>>(p);
  }
  { // gate = silu(x~ @ W_g)  (8p128 engine)
    GemmP p{}; p.A = XT; p.B = WGT; p.C = GATE;
    p.M = BT; p.N = V; p.K = D; p.lda = D; p.ldb = D; p.ldc = V;
    p.gxs = 5; p.gys = 4; p.qchunk = 64; p.swapxy = 0;
    gemm8p128_k<0, 2><<<dim3(32, 16, 1), 512, 0, stream>>>(p);
  }
  { // BD rel-shifted: scores_bd[b,i,i-d] = (qv . rr^T)[b,i,d]
    GemmP p{}; p.A = QV; p.B = RR; p.C = BD2;
    p.sA = (long)T * K; p.sB = 0; p.sC = (long)T * T;
    p.M = T; p.N = T; p.K = K; p.lda = K; p.ldb = K; p.ldc = T; p.causal = 1;
    p.gxs = 5; p.gys = 4; p.qchunk = 128;
    gemm2p_k<4, 5><<<dim3(32, 16, B), 512, 0, stream>>>(p);
  }
  { // E = exp(min(qu.k^T + BDs, 60)) causal-masked; per-(row,tile,wave) sums
    GemmP p{}; p.A = QU; p.B = KKb; p.C = EBUF;
    p.sA = (long)T * K; p.sB = (long)T * K; p.sC = (long)T * T;
    p.M = T; p.N = T; p.K = K; p.lda = K; p.ldb = K; p.ldc = T; p.causal = 1;
    p.bds = BD2; p.stats = STATS;
    p.gxs = 5; p.gys = 4; p.qchunk = 128;
    gemm2p_k<4, 6><<<dim3(32, 16, B), 512, 0, stream>>>(p);
  }
  rowinv_k<<<BT / 256, 256, 0, stream>>>(STATS, RINV, T, BT);
  { // wv = (E @ v) * rinv * gate  (8p128, paired causal balance, merged loop)
    GemmP p{}; p.A = EBUF; p.B = VVT; p.C = WVG;
    p.sA = (long)T * T; p.sB = T; p.sC = (long)T * V;
    p.M = T; p.N = V; p.K = T; p.lda = T; p.ldb = BT; p.ldc = V;
    p.kend_mode = 1; p.rinv = RINV; p.gate = GATE;
    p.gxs = 3; p.gys = 4; p.qchunk = 32;
    gemm8p128_k<1, 4><<<dim3(8, 16, 2), 512, 0, stream>>>(p);
  }
  { // res = wvg @ W_o -> fp32 out  (8p128, jj fast, merged loop)
    GemmP p{}; p.A = WVG; p.B = WOT; p.C = out;
    p.M = BT; p.N = D; p.K = V; p.lda = V; p.ldb = V; p.ldc = D;
    p.gxs = 3; p.gys = 5; p.qchunk = 32; p.swapxy = 1;
    gemm8p128_k<0, 1><<<dim3(8, 32, 1), 512, 0, stream>>>(p);
  }
}